// Round 16
// baseline (94.392 us; speedup 1.0000x reference)
//
#include <hip/hip_runtime.h>
#include <hip/hip_bf16.h>
#include <cstddef>
#include <cstdint>

#define N_NODES 50000
#define N_EDGES 800000
#define IN_CH 128
#define HID 64
#define OUT_CH 32

#define NBUCK 196    // buckets of 256 dst nodes
#define BCAP2 5120   // per-bucket region capacity (mean 4082, sigma 64, max~4267)
#define NBLK 256     // partition blocks
#define EPB 3125     // edges per partition block (256*3125 = 800000 exactly)
#define NT1 782      // gemm1 tiles (ceil(50000/64))

typedef __attribute__((ext_vector_type(8))) short bf16x8;
typedef __attribute__((ext_vector_type(8))) unsigned short u16x8;
typedef __attribute__((ext_vector_type(4))) float f32x4;

// bf16 round-to-nearest-even, bit form
__device__ __forceinline__ unsigned short bf16rne(float f) {
    union { float f; unsigned u; } c; c.f = f;
    unsigned r = c.u + 0x7FFF + ((c.u >> 16) & 1);
    return (unsigned short)(r >> 16);
}
__device__ __forceinline__ float bf16f(unsigned short b) {
    union { unsigned u; float f; } c; c.u = ((unsigned)b) << 16;
    return c.f;
}

__device__ __forceinline__ void load_edge(const void* ei, int flag, int e, int& s, int& d) {
    if (flag) {  // int64 data
        const long long* p = (const long long*)ei;
        s = (int)p[e];
        d = (int)p[e + N_EDGES];
    } else {     // int32 data
        const int* p = (const int*)ei;
        s = p[e];
        d = p[e + N_EDGES];
    }
}

// ---- zero the bucket cursors ------------------------------------------------
__global__ __launch_bounds__(256) void zerocur_kernel(int* __restrict__ cursor) {
    if (threadIdx.x < NBUCK) cursor[threadIdx.x] = 0;
}

// ---- single-pass partition (with per-block int64 detect) ------------------
// packed regions: bucket b occupies [b*BCAP2, b*BCAP2 + size_b)
__global__ __launch_bounds__(256) void scatter1_kernel(const void* ei,
                                                       int* __restrict__ cursor,
                                                       unsigned* __restrict__ packed) {
    __shared__ unsigned cbuf[EPB];   // 12.5 KB
    __shared__ int h[NBUCK];
    __shared__ int lcur[NBUCK];
    __shared__ unsigned red[256];
    const int t = threadIdx.x;
    const int base = blockIdx.x * EPB;

    // per-block int64 detect on the first 2048 odd int32 words (L2-hot)
    {
        unsigned acc = 0;
        const unsigned* w = (const unsigned*)ei;
        for (int i = t; i < 2048; i += 256) acc |= w[2 * i + 1];
        red[t] = acc;
    }
    if (t < NBUCK) h[t] = 0;
    __syncthreads();
    if (t < 128) red[t] |= red[t + 128];
    __syncthreads();
    if (t < 64) red[t] |= red[t + 64];
    __syncthreads();
    if (t == 0) {
        unsigned q = 0;
        for (int i = 0; i < 64; ++i) q |= red[i];
        red[0] = q;
    }
    __syncthreads();
    const int flag = (red[0] == 0) ? 1 : 0;

    for (int i = t; i < EPB; i += 256) {
        int s, d;
        load_edge(ei, flag, base + i, s, d);
        cbuf[i] = (unsigned)s | ((unsigned)d << 16);
        atomicAdd(&h[d >> 8], 1);
    }
    __syncthreads();
    if (t < NBUCK) lcur[t] = h[t] ? (t * BCAP2 + atomicAdd(&cursor[t], h[t])) : 0;
    __syncthreads();
    for (int i = t; i < EPB; i += 256) {
        unsigned p = cbuf[i];
        int b = p >> 24;
        int pos = atomicAdd(&lcur[b], 1);
        packed[pos] = p;
    }
}

// ---- fat kernel: blocks [0,NBUCK) bucket-sort; blocks [NBUCK,..) gemm1 ----
// rowinfo[node] = beg | deg<<20  (beg absolute into packed; beg < 2^20)
__global__ __launch_bounds__(256) void buckgemm1_kernel(
        const int* __restrict__ cursor, unsigned* __restrict__ packed,
        unsigned* __restrict__ rowinfo, float* __restrict__ dis,
        const float* __restrict__ x, const float* __restrict__ W1,
        unsigned short* __restrict__ h1b) {
    __shared__ union {
        struct { int cnt[256]; int pref[256]; int lbuf[BCAP2]; } bk;           // 22.5 KB
        struct { unsigned short xa[64][136]; unsigned short wb[64][136]; } g1; // 34.8 KB
    } u;
    const int t = threadIdx.x;

    if (blockIdx.x < NBUCK) {
        // ================= bucket counting sort =================
        const int b = blockIdx.x;
        const int nodebase = b << 8;
        const int rbase = b * BCAP2;
        const int bsize = cursor[b];
        const int nb = min(256, N_NODES - nodebase);

        u.bk.cnt[t] = 0;
        __syncthreads();
        for (int i = t; i < bsize; i += 256)
            atomicAdd(&u.bk.cnt[(packed[rbase + i] >> 16) & 255], 1);
        __syncthreads();
        const int deg = u.bk.cnt[t];
        u.bk.pref[t] = deg;
        __syncthreads();
        for (int off = 1; off < 256; off <<= 1) {
            int q = (t >= off) ? u.bk.pref[t - off] : 0;
            __syncthreads();
            u.bk.pref[t] += q;
            __syncthreads();
        }
        const int excl = u.bk.pref[t] - deg;
        if (t < nb) {
            rowinfo[nodebase + t] = (unsigned)(rbase + excl) | ((unsigned)deg << 20);
            dis[nodebase + t] = rsqrtf((float)deg + 1.0f);
        }
        __syncthreads();
        u.bk.cnt[t] = excl;  // reuse as local cursor
        __syncthreads();
        for (int i = t; i < bsize; i += 256) {
            unsigned p = packed[rbase + i];
            int pos = atomicAdd(&u.bk.cnt[(p >> 16) & 255], 1);
            u.bk.lbuf[pos] = (int)(p & 0xFFFFu);
        }
        __syncthreads();
        for (int i = t; i < bsize; i += 256)
            packed[rbase + i] = (unsigned)u.bk.lbuf[i];   // sorted src per dst
    } else {
        // ================= gemm1 tile (MFMA bf16) =================
        const int w = t >> 6;
        const int l = t & 63;
        const int brow = (blockIdx.x - NBUCK) * 64;

        for (int f = t; f < 64 * 32; f += 256) {
            int r = f >> 5, c = (f & 31) << 2;
            int gr = brow + r;
            float4 v = (gr < N_NODES) ? *(const float4*)(x + gr * IN_CH + c)
                                      : make_float4(0.f, 0.f, 0.f, 0.f);
            u.g1.xa[r][c + 0] = bf16rne(v.x); u.g1.xa[r][c + 1] = bf16rne(v.y);
            u.g1.xa[r][c + 2] = bf16rne(v.z); u.g1.xa[r][c + 3] = bf16rne(v.w);
        }
        for (int f = t; f < 128 * 16; f += 256) {
            int k = f >> 4, n = (f & 15) << 2;
            float4 v = *(const float4*)(W1 + k * HID + n);
            u.g1.wb[n + 0][k] = bf16rne(v.x); u.g1.wb[n + 1][k] = bf16rne(v.y);
            u.g1.wb[n + 2][k] = bf16rne(v.z); u.g1.wb[n + 3][k] = bf16rne(v.w);
        }
        __syncthreads();

        const int fr = l & 15;
        const int fk = (l >> 4) << 3;
        f32x4 acc[4] = {{0.f,0.f,0.f,0.f},{0.f,0.f,0.f,0.f},
                        {0.f,0.f,0.f,0.f},{0.f,0.f,0.f,0.f}};
#pragma unroll
        for (int kb = 0; kb < 4; ++kb) {
            const int k = kb * 32 + fk;
            bf16x8 a = *(const bf16x8*)&u.g1.xa[w * 16 + fr][k];
#pragma unroll
            for (int n = 0; n < 4; ++n) {
                bf16x8 bfr = *(const bf16x8*)&u.g1.wb[n * 16 + fr][k];
                acc[n] = __builtin_amdgcn_mfma_f32_16x16x32_bf16(a, bfr, acc[n], 0, 0, 0);
            }
        }
        const int rb = brow + w * 16 + ((l >> 4) << 2);
#pragma unroll
        for (int n = 0; n < 4; ++n) {
#pragma unroll
            for (int i = 0; i < 4; ++i) {
                int r = rb + i;
                if (r < N_NODES) h1b[r * HID + n * 16 + fr] = bf16rne(acc[n][i]);
            }
        }
    }
}

// ---- scale h1 rows by dis[row] in place: h1s = h1 * dis -------------------
// 8 threads per node, one u16x8 (8 channels) each.
__global__ __launch_bounds__(256) void scaleh1_kernel(const float* __restrict__ dis,
                                                      unsigned short* __restrict__ h1b) {
    const int i = blockIdx.x * 256 + threadIdx.x;
    if (i >= N_NODES * 8) return;
    const int node = i >> 3;
    const int part = (i & 7) << 3;
    const float dd = dis[node];
    u16x8 v = *(const u16x8*)(h1b + node * HID + part);
    u16x8 o;
#pragma unroll
    for (int c = 0; c < 8; ++c) o[c] = bf16rne(bf16f(v[c]) * dd);
    *(u16x8*)(h1b + node * HID + part) = o;
}

// ---- fused agg1 + gemm2: block of 16 waves owns 64 consecutive dsts -------
// h1b is PRE-SCALED by dis[src]; agg loop is pure gather+add, final ×dd.
// gemm2 epilogue pre-scales h2 rows by dis[row] for agg2.
__global__ __launch_bounds__(1024) void agg1gemm2_kernel(
        const unsigned* __restrict__ rowinfo, const unsigned* __restrict__ sorted,
        const float* __restrict__ dis, const unsigned short* __restrict__ h1b,
        const float* __restrict__ b1, const float* __restrict__ W2,
        unsigned short* __restrict__ h2b) {
    __shared__ unsigned short xa[64][72];   // agg1 tile, bf16, +8 pad (9.2 KB)
    __shared__ unsigned short wb[32][72];   // W2 transposed [n][k] (4.6 KB)
    const int t = threadIdx.x;
    const int w = t >> 6;    // wave 0..15
    const int l = t & 63;
    const int g = l >> 3;    // edge group 0-7
    const int cl = l & 7;    // 8 channels: 8cl..8cl+7
    const int base = blockIdx.x * 64;

    // stage W2^T bf16 (first 512 threads; read before any sync)
    if (t < 512) {
        int k = t >> 3, n = (t & 7) << 2;
        float4 v = *(const float4*)(W2 + k * OUT_CH + n);
        wb[n + 0][k] = bf16rne(v.x); wb[n + 1][k] = bf16rne(v.y);
        wb[n + 2][k] = bf16rne(v.z); wb[n + 3][k] = bf16rne(v.w);
    }

    // ---- agg phase: wave w handles rows 4w..4w+3 ----
#pragma unroll
    for (int q = 0; q < 4; ++q) {
        const int row = w * 4 + q;
        const int d = base + row;          // wave-uniform
        float a0 = 0.f, a1 = 0.f, a2 = 0.f, a3 = 0.f;
        float a4 = 0.f, a5 = 0.f, a6 = 0.f, a7 = 0.f;
        if (d < N_NODES) {
            const unsigned ri = rowinfo[d];
            const int beg = (int)(ri & 0xFFFFFu);
            const int end = beg + (int)(ri >> 20);
            const float dd = dis[d];
            int j = beg + g;
            for (; j + 8 < end; j += 16) {
                int s0 = (int)sorted[j];
                int s1 = (int)sorted[j + 8];
                bf16x8 h0 = *(const bf16x8*)(h1b + s0 * HID + 8 * cl);
                bf16x8 h1v = *(const bf16x8*)(h1b + s1 * HID + 8 * cl);
                a0 += bf16f((unsigned short)h0[0]); a1 += bf16f((unsigned short)h0[1]);
                a2 += bf16f((unsigned short)h0[2]); a3 += bf16f((unsigned short)h0[3]);
                a4 += bf16f((unsigned short)h0[4]); a5 += bf16f((unsigned short)h0[5]);
                a6 += bf16f((unsigned short)h0[6]); a7 += bf16f((unsigned short)h0[7]);
                a0 += bf16f((unsigned short)h1v[0]); a1 += bf16f((unsigned short)h1v[1]);
                a2 += bf16f((unsigned short)h1v[2]); a3 += bf16f((unsigned short)h1v[3]);
                a4 += bf16f((unsigned short)h1v[4]); a5 += bf16f((unsigned short)h1v[5]);
                a6 += bf16f((unsigned short)h1v[6]); a7 += bf16f((unsigned short)h1v[7]);
            }
            if (j < end) {
                int s0 = (int)sorted[j];
                bf16x8 h0 = *(const bf16x8*)(h1b + s0 * HID + 8 * cl);
                a0 += bf16f((unsigned short)h0[0]); a1 += bf16f((unsigned short)h0[1]);
                a2 += bf16f((unsigned short)h0[2]); a3 += bf16f((unsigned short)h0[3]);
                a4 += bf16f((unsigned short)h0[4]); a5 += bf16f((unsigned short)h0[5]);
                a6 += bf16f((unsigned short)h0[6]); a7 += bf16f((unsigned short)h0[7]);
            }
#pragma unroll
            for (int st = 8; st <= 32; st <<= 1) {
                a0 += __shfl_xor(a0, st, 64); a1 += __shfl_xor(a1, st, 64);
                a2 += __shfl_xor(a2, st, 64); a3 += __shfl_xor(a3, st, 64);
                a4 += __shfl_xor(a4, st, 64); a5 += __shfl_xor(a5, st, 64);
                a6 += __shfl_xor(a6, st, 64); a7 += __shfl_xor(a7, st, 64);
            }
            if (g == 0) {
                // self-loop: h1s[d]*dd = h1[d]*dis[d]*dd = h1[d]*dd^2  -> joins sum
                bf16x8 hs = *(const bf16x8*)(h1b + d * HID + 8 * cl);
                float4 bv0 = *(const float4*)(b1 + 8 * cl);
                float4 bv1 = *(const float4*)(b1 + 8 * cl + 4);
                u16x8 o;
                o[0] = bf16rne(fmaxf(dd * (a0 + bf16f((unsigned short)hs[0])) + bv0.x, 0.f));
                o[1] = bf16rne(fmaxf(dd * (a1 + bf16f((unsigned short)hs[1])) + bv0.y, 0.f));
                o[2] = bf16rne(fmaxf(dd * (a2 + bf16f((unsigned short)hs[2])) + bv0.z, 0.f));
                o[3] = bf16rne(fmaxf(dd * (a3 + bf16f((unsigned short)hs[3])) + bv0.w, 0.f));
                o[4] = bf16rne(fmaxf(dd * (a4 + bf16f((unsigned short)hs[4])) + bv1.x, 0.f));
                o[5] = bf16rne(fmaxf(dd * (a5 + bf16f((unsigned short)hs[5])) + bv1.y, 0.f));
                o[6] = bf16rne(fmaxf(dd * (a6 + bf16f((unsigned short)hs[6])) + bv1.z, 0.f));
                o[7] = bf16rne(fmaxf(dd * (a7 + bf16f((unsigned short)hs[7])) + bv1.w, 0.f));
                *(u16x8*)&xa[row][8 * cl] = o;
            }
        } else if (g == 0) {
            u16x8 z = {0, 0, 0, 0, 0, 0, 0, 0};
            *(u16x8*)&xa[row][8 * cl] = z;
        }
    }
    __syncthreads();

    // ---- gemm2 phase: waves 0..7, each 16 rows x 16 cols, K=64 ----
    // epilogue pre-scales h2 rows by dis[row] (for agg2's factorized norm).
    if (w < 8) {
        const int rt = (w >> 1) << 4;   // 0,16,32,48
        const int ct = (w & 1) << 4;    // 0,16
        const int fr = l & 15;
        const int fk = (l >> 4) << 3;
        f32x4 acc = {0.f, 0.f, 0.f, 0.f};
#pragma unroll
        for (int kb = 0; kb < 2; ++kb) {
            const int k = kb * 32 + fk;
            bf16x8 a = *(const bf16x8*)&xa[rt + fr][k];
            bf16x8 bfr = *(const bf16x8*)&wb[ct + fr][k];
            acc = __builtin_amdgcn_mfma_f32_16x16x32_bf16(a, bfr, acc, 0, 0, 0);
        }
        const int rb = base + rt + ((l >> 4) << 2);
#pragma unroll
        for (int i = 0; i < 4; ++i) {
            int r = rb + i;
            if (r < N_NODES) h2b[r * OUT_CH + ct + fr] = bf16rne(acc[i] * dis[r]);
        }
    }
}

// ---- agg2: wave per dst; 16 groups x 4 lanes; h2b pre-scaled by dis[src] --
// out[d][c] = dd * ( sum_j h2s[src_j][c] + h2s[d][c] ) + b2[c]
__global__ __launch_bounds__(256) void agg2_kernel(
        const unsigned* __restrict__ rowinfo, const unsigned* __restrict__ sorted,
        const float* __restrict__ dis, const unsigned short* __restrict__ h2b,
        const float* __restrict__ b2, float* __restrict__ out) {
    const int l = threadIdx.x & 63;
    const int g = l >> 2;    // edge group 0-15
    const int cl = l & 3;    // 8 channels: 8cl..8cl+7
    const int d = blockIdx.x * 4 + (threadIdx.x >> 6);
    if (d >= N_NODES) return;
    const unsigned ri = rowinfo[d];
    const int beg = (int)(ri & 0xFFFFFu);
    const int end = beg + (int)(ri >> 20);
    const float dd = dis[d];
    float a0 = 0.f, a1 = 0.f, a2 = 0.f, a3 = 0.f;
    float a4 = 0.f, a5 = 0.f, a6 = 0.f, a7 = 0.f;
    for (int j = beg + g; j < end; j += 16) {
        int s = (int)sorted[j];
        bf16x8 h = *(const bf16x8*)(h2b + s * OUT_CH + 8 * cl);
        a0 += bf16f((unsigned short)h[0]); a1 += bf16f((unsigned short)h[1]);
        a2 += bf16f((unsigned short)h[2]); a3 += bf16f((unsigned short)h[3]);
        a4 += bf16f((unsigned short)h[4]); a5 += bf16f((unsigned short)h[5]);
        a6 += bf16f((unsigned short)h[6]); a7 += bf16f((unsigned short)h[7]);
    }
#pragma unroll
    for (int st = 4; st <= 32; st <<= 1) {
        a0 += __shfl_xor(a0, st, 64); a1 += __shfl_xor(a1, st, 64);
        a2 += __shfl_xor(a2, st, 64); a3 += __shfl_xor(a3, st, 64);
        a4 += __shfl_xor(a4, st, 64); a5 += __shfl_xor(a5, st, 64);
        a6 += __shfl_xor(a6, st, 64); a7 += __shfl_xor(a7, st, 64);
    }
    if (g == 0) {
        bf16x8 hs = *(const bf16x8*)(h2b + d * OUT_CH + 8 * cl);
        float4 bv0 = *(const float4*)(b2 + 8 * cl);
        float4 bv1 = *(const float4*)(b2 + 8 * cl + 4);
        float4 o0, o1;
        o0.x = dd * (a0 + bf16f((unsigned short)hs[0])) + bv0.x;
        o0.y = dd * (a1 + bf16f((unsigned short)hs[1])) + bv0.y;
        o0.z = dd * (a2 + bf16f((unsigned short)hs[2])) + bv0.z;
        o0.w = dd * (a3 + bf16f((unsigned short)hs[3])) + bv0.w;
        o1.x = dd * (a4 + bf16f((unsigned short)hs[4])) + bv1.x;
        o1.y = dd * (a5 + bf16f((unsigned short)hs[5])) + bv1.y;
        o1.z = dd * (a6 + bf16f((unsigned short)hs[6])) + bv1.z;
        o1.w = dd * (a7 + bf16f((unsigned short)hs[7])) + bv1.w;
        *(float4*)(out + d * OUT_CH + 8 * cl) = o0;
        *(float4*)(out + d * OUT_CH + 8 * cl + 4) = o1;
    }
}

extern "C" void kernel_launch(void* const* d_in, const int* in_sizes, int n_in,
                              void* d_out, int out_size, void* d_ws, size_t ws_size,
                              hipStream_t stream) {
    const float* x  = (const float*)d_in[0];
    const float* W1 = (const float*)d_in[1];
    const float* b1 = (const float*)d_in[2];
    const float* W2 = (const float*)d_in[3];
    const float* b2 = (const float*)d_in[4];
    const void*  ei = d_in[5];
    float* out = (float*)d_out;

    char* wp = (char*)d_ws;
    auto alloc = [&](size_t n) { char* p = wp; wp += (n + 511) & ~(size_t)511; return p; };
    int*   cursor  = (int*)alloc(NBUCK * 4);
    unsigned* rowinfo = (unsigned*)alloc((size_t)N_NODES * 4);   // 200 KB
    float* dis     = (float*)alloc((size_t)N_NODES * 4);         // 200 KB
    unsigned* packed = (unsigned*)alloc((size_t)NBUCK * BCAP2 * 4);       // 4.0 MB
    unsigned short* h1b = (unsigned short*)alloc((size_t)N_NODES * HID * 2);    // 6.4 MB
    unsigned short* h2b = (unsigned short*)alloc((size_t)N_NODES * OUT_CH * 2); // 3.2 MB

    zerocur_kernel<<<1, 256, 0, stream>>>(cursor);
    scatter1_kernel<<<NBLK, 256, 0, stream>>>(ei, cursor, packed);
    buckgemm1_kernel<<<NBUCK + NT1, 256, 0, stream>>>(cursor, packed, rowinfo, dis,
                                                      x, W1, h1b);
    scaleh1_kernel<<<(N_NODES * 8 + 255) / 256, 256, 0, stream>>>(dis, h1b);
    agg1gemm2_kernel<<<NT1, 1024, 0, stream>>>(rowinfo, packed, dis, h1b, b1, W2, h2b);
    agg2_kernel<<<(N_NODES + 3) / 4, 256, 0, stream>>>(rowinfo, packed, dis, h2b, b2, out);
}

// Round 17
// 90.542 us; speedup vs baseline: 1.0425x; 1.0425x over previous
//
#include <hip/hip_runtime.h>
#include <hip/hip_bf16.h>
#include <cstddef>
#include <cstdint>

#define N_NODES 50000
#define N_EDGES 800000
#define IN_CH 128
#define HID 64
#define OUT_CH 32

#define NBUCK 196    // buckets of 256 dst nodes
#define BCAP2 5120   // per-bucket region capacity (mean 4082, sigma 64, max~4267)
#define NBLK 256     // partition blocks
#define EPB 3125     // edges per partition block (256*3125 = 800000 exactly)
#define NT1 782      // gemm1 tiles (ceil(50000/64))

typedef __attribute__((ext_vector_type(8))) short bf16x8;
typedef __attribute__((ext_vector_type(8))) unsigned short u16x8;
typedef __attribute__((ext_vector_type(4))) float f32x4;

// bf16 round-to-nearest-even, bit form
__device__ __forceinline__ unsigned short bf16rne(float f) {
    union { float f; unsigned u; } c; c.f = f;
    unsigned r = c.u + 0x7FFF + ((c.u >> 16) & 1);
    return (unsigned short)(r >> 16);
}
__device__ __forceinline__ float bf16f(unsigned short b) {
    union { unsigned u; float f; } c; c.u = ((unsigned)b) << 16;
    return c.f;
}

__device__ __forceinline__ void load_edge(const void* ei, int flag, int e, int& s, int& d) {
    if (flag) {  // int64 data
        const long long* p = (const long long*)ei;
        s = (int)p[e];
        d = (int)p[e + N_EDGES];
    } else {     // int32 data
        const int* p = (const int*)ei;
        s = p[e];
        d = p[e + N_EDGES];
    }
}

// ---- zero the bucket cursors ------------------------------------------------
__global__ __launch_bounds__(256) void zerocur_kernel(int* __restrict__ cursor) {
    if (threadIdx.x < NBUCK) cursor[threadIdx.x] = 0;
}

// ---- single-pass partition (with per-block int64 detect) ------------------
// packed regions: bucket b occupies [b*BCAP2, b*BCAP2 + size_b)
__global__ __launch_bounds__(256) void scatter1_kernel(const void* ei,
                                                       int* __restrict__ cursor,
                                                       unsigned* __restrict__ packed) {
    __shared__ unsigned cbuf[EPB];   // 12.5 KB
    __shared__ int h[NBUCK];
    __shared__ int lcur[NBUCK];
    __shared__ unsigned red[256];
    const int t = threadIdx.x;
    const int base = blockIdx.x * EPB;

    // per-block int64 detect on the first 2048 odd int32 words (L2-hot)
    {
        unsigned acc = 0;
        const unsigned* w = (const unsigned*)ei;
        for (int i = t; i < 2048; i += 256) acc |= w[2 * i + 1];
        red[t] = acc;
    }
    if (t < NBUCK) h[t] = 0;
    __syncthreads();
    if (t < 128) red[t] |= red[t + 128];
    __syncthreads();
    if (t < 64) red[t] |= red[t + 64];
    __syncthreads();
    if (t == 0) {
        unsigned q = 0;
        for (int i = 0; i < 64; ++i) q |= red[i];
        red[0] = q;
    }
    __syncthreads();
    const int flag = (red[0] == 0) ? 1 : 0;

    for (int i = t; i < EPB; i += 256) {
        int s, d;
        load_edge(ei, flag, base + i, s, d);
        cbuf[i] = (unsigned)s | ((unsigned)d << 16);
        atomicAdd(&h[d >> 8], 1);
    }
    __syncthreads();
    if (t < NBUCK) lcur[t] = h[t] ? (t * BCAP2 + atomicAdd(&cursor[t], h[t])) : 0;
    __syncthreads();
    for (int i = t; i < EPB; i += 256) {
        unsigned p = cbuf[i];
        int b = p >> 24;
        int pos = atomicAdd(&lcur[b], 1);
        packed[pos] = p;
    }
}

// ---- fat kernel: blocks [0,NBUCK) bucket-sort; blocks [NBUCK,..) gemm1 ----
// rowinfo[node] = beg | deg<<20  (beg absolute into packed; beg < 2^20)
__global__ __launch_bounds__(256) void buckgemm1_kernel(
        const int* __restrict__ cursor, unsigned* __restrict__ packed,
        unsigned* __restrict__ rowinfo, float* __restrict__ dis,
        const float* __restrict__ x, const float* __restrict__ W1,
        unsigned short* __restrict__ h1b) {
    __shared__ union {
        struct { int cnt[256]; int pref[256]; int lbuf[BCAP2]; } bk;           // 22.5 KB
        struct { unsigned short xa[64][136]; unsigned short wb[64][136]; } g1; // 34.8 KB
    } u;
    const int t = threadIdx.x;

    if (blockIdx.x < NBUCK) {
        // ================= bucket counting sort =================
        const int b = blockIdx.x;
        const int nodebase = b << 8;
        const int rbase = b * BCAP2;
        const int bsize = cursor[b];
        const int nb = min(256, N_NODES - nodebase);

        u.bk.cnt[t] = 0;
        __syncthreads();
        for (int i = t; i < bsize; i += 256)
            atomicAdd(&u.bk.cnt[(packed[rbase + i] >> 16) & 255], 1);
        __syncthreads();
        const int deg = u.bk.cnt[t];
        u.bk.pref[t] = deg;
        __syncthreads();
        for (int off = 1; off < 256; off <<= 1) {
            int q = (t >= off) ? u.bk.pref[t - off] : 0;
            __syncthreads();
            u.bk.pref[t] += q;
            __syncthreads();
        }
        const int excl = u.bk.pref[t] - deg;
        if (t < nb) {
            rowinfo[nodebase + t] = (unsigned)(rbase + excl) | ((unsigned)deg << 20);
            dis[nodebase + t] = rsqrtf((float)deg + 1.0f);
        }
        __syncthreads();
        u.bk.cnt[t] = excl;  // reuse as local cursor
        __syncthreads();
        for (int i = t; i < bsize; i += 256) {
            unsigned p = packed[rbase + i];
            int pos = atomicAdd(&u.bk.cnt[(p >> 16) & 255], 1);
            u.bk.lbuf[pos] = (int)(p & 0xFFFFu);
        }
        __syncthreads();
        for (int i = t; i < bsize; i += 256)
            packed[rbase + i] = (unsigned)u.bk.lbuf[i];   // sorted src per dst
    } else {
        // ================= gemm1 tile (MFMA bf16) =================
        const int w = t >> 6;
        const int l = t & 63;
        const int brow = (blockIdx.x - NBUCK) * 64;

        for (int f = t; f < 64 * 32; f += 256) {
            int r = f >> 5, c = (f & 31) << 2;
            int gr = brow + r;
            float4 v = (gr < N_NODES) ? *(const float4*)(x + gr * IN_CH + c)
                                      : make_float4(0.f, 0.f, 0.f, 0.f);
            u.g1.xa[r][c + 0] = bf16rne(v.x); u.g1.xa[r][c + 1] = bf16rne(v.y);
            u.g1.xa[r][c + 2] = bf16rne(v.z); u.g1.xa[r][c + 3] = bf16rne(v.w);
        }
        for (int f = t; f < 128 * 16; f += 256) {
            int k = f >> 4, n = (f & 15) << 2;
            float4 v = *(const float4*)(W1 + k * HID + n);
            u.g1.wb[n + 0][k] = bf16rne(v.x); u.g1.wb[n + 1][k] = bf16rne(v.y);
            u.g1.wb[n + 2][k] = bf16rne(v.z); u.g1.wb[n + 3][k] = bf16rne(v.w);
        }
        __syncthreads();

        const int fr = l & 15;
        const int fk = (l >> 4) << 3;
        f32x4 acc[4] = {{0.f,0.f,0.f,0.f},{0.f,0.f,0.f,0.f},
                        {0.f,0.f,0.f,0.f},{0.f,0.f,0.f,0.f}};
#pragma unroll
        for (int kb = 0; kb < 4; ++kb) {
            const int k = kb * 32 + fk;
            bf16x8 a = *(const bf16x8*)&u.g1.xa[w * 16 + fr][k];
#pragma unroll
            for (int n = 0; n < 4; ++n) {
                bf16x8 bfr = *(const bf16x8*)&u.g1.wb[n * 16 + fr][k];
                acc[n] = __builtin_amdgcn_mfma_f32_16x16x32_bf16(a, bfr, acc[n], 0, 0, 0);
            }
        }
        const int rb = brow + w * 16 + ((l >> 4) << 2);
#pragma unroll
        for (int n = 0; n < 4; ++n) {
#pragma unroll
            for (int i = 0; i < 4; ++i) {
                int r = rb + i;
                if (r < N_NODES) h1b[r * HID + n * 16 + fr] = bf16rne(acc[n][i]);
            }
        }
    }
}

// ---- agg1: wave per dst; 8 groups x 8 lanes, bf16x8 (16B) gathers ---------
__global__ __launch_bounds__(256) void agg1_kernel(
        const unsigned* __restrict__ rowinfo, const unsigned* __restrict__ sorted,
        const float* __restrict__ dis, const unsigned short* __restrict__ h1b,
        const float* __restrict__ b1, unsigned short* __restrict__ agg1b) {
    const int l = threadIdx.x & 63;
    const int g = l >> 3;    // edge group 0-7
    const int cl = l & 7;    // 8 channels: 8cl..8cl+7
    const int d = blockIdx.x * 4 + (threadIdx.x >> 6);
    if (d >= N_NODES) return;
    const unsigned ri = rowinfo[d];
    const int beg = (int)(ri & 0xFFFFFu);
    const int end = beg + (int)(ri >> 20);
    const float dd = dis[d];
    float a0 = 0.f, a1 = 0.f, a2 = 0.f, a3 = 0.f;
    float a4 = 0.f, a5 = 0.f, a6 = 0.f, a7 = 0.f;
    for (int j = beg + g; j < end; j += 8) {
        int s = (int)sorted[j];
        float n = dis[s] * dd;
        bf16x8 h = *(const bf16x8*)(h1b + s * HID + 8 * cl);
        a0 += bf16f((unsigned short)h[0]) * n; a1 += bf16f((unsigned short)h[1]) * n;
        a2 += bf16f((unsigned short)h[2]) * n; a3 += bf16f((unsigned short)h[3]) * n;
        a4 += bf16f((unsigned short)h[4]) * n; a5 += bf16f((unsigned short)h[5]) * n;
        a6 += bf16f((unsigned short)h[6]) * n; a7 += bf16f((unsigned short)h[7]) * n;
    }
#pragma unroll
    for (int st = 8; st <= 32; st <<= 1) {
        a0 += __shfl_xor(a0, st, 64); a1 += __shfl_xor(a1, st, 64);
        a2 += __shfl_xor(a2, st, 64); a3 += __shfl_xor(a3, st, 64);
        a4 += __shfl_xor(a4, st, 64); a5 += __shfl_xor(a5, st, 64);
        a6 += __shfl_xor(a6, st, 64); a7 += __shfl_xor(a7, st, 64);
    }
    if (g == 0) {
        bf16x8 hs = *(const bf16x8*)(h1b + d * HID + 8 * cl);
        float4 bv0 = *(const float4*)(b1 + 8 * cl);
        float4 bv1 = *(const float4*)(b1 + 8 * cl + 4);
        float d2 = dd * dd;
        u16x8 o;
        o[0] = bf16rne(fmaxf(a0 + bf16f((unsigned short)hs[0]) * d2 + bv0.x, 0.f));
        o[1] = bf16rne(fmaxf(a1 + bf16f((unsigned short)hs[1]) * d2 + bv0.y, 0.f));
        o[2] = bf16rne(fmaxf(a2 + bf16f((unsigned short)hs[2]) * d2 + bv0.z, 0.f));
        o[3] = bf16rne(fmaxf(a3 + bf16f((unsigned short)hs[3]) * d2 + bv0.w, 0.f));
        o[4] = bf16rne(fmaxf(a4 + bf16f((unsigned short)hs[4]) * d2 + bv1.x, 0.f));
        o[5] = bf16rne(fmaxf(a5 + bf16f((unsigned short)hs[5]) * d2 + bv1.y, 0.f));
        o[6] = bf16rne(fmaxf(a6 + bf16f((unsigned short)hs[6]) * d2 + bv1.z, 0.f));
        o[7] = bf16rne(fmaxf(a7 + bf16f((unsigned short)hs[7]) * d2 + bv1.w, 0.f));
        *(u16x8*)(agg1b + d * HID + 8 * cl) = o;
    }
}

// --------------- GEMM2 (MFMA bf16): h2b = bf16(agg1b @ W2) -----------------
__global__ __launch_bounds__(256) void gemm2_kernel(
        const unsigned short* __restrict__ agg1b, const float* __restrict__ W2,
        unsigned short* __restrict__ h2b) {
    __shared__ unsigned short xa[64][72];   // agg1b tile (64x64), +8 pad
    __shared__ unsigned short wb[32][72];   // W2 transposed [n][k]
    const int t = threadIdx.x;
    const int w = t >> 6;
    const int l = t & 63;
    const int brow = blockIdx.x * 64;

    for (int f = t; f < 64 * 16; f += 256) {
        int r = f >> 4, c = (f & 15) << 2;
        int gr = brow + r;
        ushort4 v = make_ushort4(0, 0, 0, 0);
        if (gr < N_NODES) v = *(const ushort4*)(agg1b + gr * HID + c);
        *(ushort4*)&xa[r][c] = v;
    }
    for (int f = t; f < 64 * 8; f += 256) {
        int k = f >> 3, n = (f & 7) << 2;
        float4 v = *(const float4*)(W2 + k * OUT_CH + n);
        wb[n + 0][k] = bf16rne(v.x); wb[n + 1][k] = bf16rne(v.y);
        wb[n + 2][k] = bf16rne(v.z); wb[n + 3][k] = bf16rne(v.w);
    }
    __syncthreads();

    const int fr = l & 15;
    const int fk = (l >> 4) << 3;
    f32x4 acc[2] = {{0.f,0.f,0.f,0.f},{0.f,0.f,0.f,0.f}};
#pragma unroll
    for (int kb = 0; kb < 2; ++kb) {
        const int k = kb * 32 + fk;
        bf16x8 a = *(const bf16x8*)&xa[w * 16 + fr][k];
#pragma unroll
        for (int n = 0; n < 2; ++n) {
            bf16x8 bfr = *(const bf16x8*)&wb[n * 16 + fr][k];
            acc[n] = __builtin_amdgcn_mfma_f32_16x16x32_bf16(a, bfr, acc[n], 0, 0, 0);
        }
    }
    const int rb = brow + w * 16 + ((l >> 4) << 2);
#pragma unroll
    for (int n = 0; n < 2; ++n) {
#pragma unroll
        for (int i = 0; i < 4; ++i) {
            int r = rb + i;
            if (r < N_NODES) h2b[r * OUT_CH + n * 16 + fr] = bf16rne(acc[n][i]);
        }
    }
}

// ---- agg2: wave per dst; 16 groups x 4 lanes, bf16x8 (16B) gathers --------
__global__ __launch_bounds__(256) void agg2_kernel(
        const unsigned* __restrict__ rowinfo, const unsigned* __restrict__ sorted,
        const float* __restrict__ dis, const unsigned short* __restrict__ h2b,
        const float* __restrict__ b2, float* __restrict__ out) {
    const int l = threadIdx.x & 63;
    const int g = l >> 2;    // edge group 0-15
    const int cl = l & 3;    // 8 channels: 8cl..8cl+7
    const int d = blockIdx.x * 4 + (threadIdx.x >> 6);
    if (d >= N_NODES) return;
    const unsigned ri = rowinfo[d];
    const int beg = (int)(ri & 0xFFFFFu);
    const int end = beg + (int)(ri >> 20);
    const float dd = dis[d];
    float a0 = 0.f, a1 = 0.f, a2 = 0.f, a3 = 0.f;
    float a4 = 0.f, a5 = 0.f, a6 = 0.f, a7 = 0.f;
    for (int j = beg + g; j < end; j += 16) {
        int s = (int)sorted[j];
        float n = dis[s] * dd;
        bf16x8 h = *(const bf16x8*)(h2b + s * OUT_CH + 8 * cl);
        a0 += bf16f((unsigned short)h[0]) * n; a1 += bf16f((unsigned short)h[1]) * n;
        a2 += bf16f((unsigned short)h[2]) * n; a3 += bf16f((unsigned short)h[3]) * n;
        a4 += bf16f((unsigned short)h[4]) * n; a5 += bf16f((unsigned short)h[5]) * n;
        a6 += bf16f((unsigned short)h[6]) * n; a7 += bf16f((unsigned short)h[7]) * n;
    }
#pragma unroll
    for (int st = 4; st <= 32; st <<= 1) {
        a0 += __shfl_xor(a0, st, 64); a1 += __shfl_xor(a1, st, 64);
        a2 += __shfl_xor(a2, st, 64); a3 += __shfl_xor(a3, st, 64);
        a4 += __shfl_xor(a4, st, 64); a5 += __shfl_xor(a5, st, 64);
        a6 += __shfl_xor(a6, st, 64); a7 += __shfl_xor(a7, st, 64);
    }
    if (g == 0) {
        bf16x8 hs = *(const bf16x8*)(h2b + d * OUT_CH + 8 * cl);
        float4 bv0 = *(const float4*)(b2 + 8 * cl);
        float4 bv1 = *(const float4*)(b2 + 8 * cl + 4);
        float d2 = dd * dd;
        float4 o0, o1;
        o0.x = a0 + bf16f((unsigned short)hs[0]) * d2 + bv0.x;
        o0.y = a1 + bf16f((unsigned short)hs[1]) * d2 + bv0.y;
        o0.z = a2 + bf16f((unsigned short)hs[2]) * d2 + bv0.z;
        o0.w = a3 + bf16f((unsigned short)hs[3]) * d2 + bv0.w;
        o1.x = a4 + bf16f((unsigned short)hs[4]) * d2 + bv1.x;
        o1.y = a5 + bf16f((unsigned short)hs[5]) * d2 + bv1.y;
        o1.z = a6 + bf16f((unsigned short)hs[6]) * d2 + bv1.z;
        o1.w = a7 + bf16f((unsigned short)hs[7]) * d2 + bv1.w;
        *(float4*)(out + d * OUT_CH + 8 * cl) = o0;
        *(float4*)(out + d * OUT_CH + 8 * cl + 4) = o1;
    }
}

extern "C" void kernel_launch(void* const* d_in, const int* in_sizes, int n_in,
                              void* d_out, int out_size, void* d_ws, size_t ws_size,
                              hipStream_t stream) {
    const float* x  = (const float*)d_in[0];
    const float* W1 = (const float*)d_in[1];
    const float* b1 = (const float*)d_in[2];
    const float* W2 = (const float*)d_in[3];
    const float* b2 = (const float*)d_in[4];
    const void*  ei = d_in[5];
    float* out = (float*)d_out;

    char* wp = (char*)d_ws;
    auto alloc = [&](size_t n) { char* p = wp; wp += (n + 511) & ~(size_t)511; return p; };
    int*   cursor  = (int*)alloc(NBUCK * 4);
    unsigned* rowinfo = (unsigned*)alloc((size_t)N_NODES * 4);   // 200 KB
    float* dis     = (float*)alloc((size_t)N_NODES * 4);         // 200 KB
    unsigned* packed = (unsigned*)alloc((size_t)NBUCK * BCAP2 * 4);       // 4.0 MB
    unsigned short* h1b = (unsigned short*)alloc((size_t)N_NODES * HID * 2);    // 6.4 MB
    unsigned short* agg1b = (unsigned short*)alloc((size_t)N_NODES * HID * 2);  // 6.4 MB
    unsigned short* h2b = (unsigned short*)alloc((size_t)N_NODES * OUT_CH * 2); // 3.2 MB

    zerocur_kernel<<<1, 256, 0, stream>>>(cursor);
    scatter1_kernel<<<NBLK, 256, 0, stream>>>(ei, cursor, packed);
    buckgemm1_kernel<<<NBUCK + NT1, 256, 0, stream>>>(cursor, packed, rowinfo, dis,
                                                      x, W1, h1b);
    agg1_kernel<<<(N_NODES + 3) / 4, 256, 0, stream>>>(rowinfo, packed, dis, h1b, b1, agg1b);
    gemm2_kernel<<<(N_NODES + 63) / 64, 256, 0, stream>>>(agg1b, W2, h2b);
    agg2_kernel<<<(N_NODES + 3) / 4, 256, 0, stream>>>(rowinfo, packed, dis, h2b, b2, out);
}